// Round 3
// baseline (809.074 us; speedup 1.0000x reference)
//
#include <hip/hip_runtime.h>
#include <hip/hip_bf16.h>

#define IN_F 128
#define DF   256
#define HEADS 4
#define CPH  64
#define NEG  0.2f
#define LN_EPS 1e-5f

__device__ __forceinline__ float lrelu(float x) { return x > 0.f ? x : NEG * x; }

// ---------------- K1: h = x @ W  (store bf16), fused a_s/a_d ----------------
// block: 256 threads, handles 16 rows. thread t owns output dim d = t.
// head = t>>6 == wave id, so per-head attention dot is a 64-lane wave reduce.
__global__ __launch_bounds__(256) void k_gemm(
        const float* __restrict__ x, const float* __restrict__ W,
        const float* __restrict__ att_s, const float* __restrict__ att_d,
        __hip_bfloat16* __restrict__ hb,
        float* __restrict__ a_s, float* __restrict__ a_d, int N)
{
    __shared__ float xs[16 * IN_F];
    int t = threadIdx.x;
    int row0 = blockIdx.x * 16;

    const float4* xg = (const float4*)(x + (size_t)row0 * IN_F);
    float4* xs4 = (float4*)xs;
    #pragma unroll
    for (int j = 0; j < 2; ++j) {
        int s = t + j * 256;              // 512 float4 slots = 16 rows x 32
        if (row0 + (s >> 5) < N) xs4[s] = xg[s];
        else xs4[s] = make_float4(0.f, 0.f, 0.f, 0.f);
    }
    __syncthreads();

    float acc[16];
    #pragma unroll
    for (int r = 0; r < 16; ++r) acc[r] = 0.f;

    const float* Wc = W + t;
    for (int k0 = 0; k0 < IN_F; k0 += 4) {
        float w0 = Wc[(k0 + 0) * DF];
        float w1 = Wc[(k0 + 1) * DF];
        float w2 = Wc[(k0 + 2) * DF];
        float w3 = Wc[(k0 + 3) * DF];
        #pragma unroll
        for (int r = 0; r < 16; ++r) {
            float4 xv = xs4[r * 32 + (k0 >> 2)];
            acc[r] = fmaf(xv.x, w0, fmaf(xv.y, w1, fmaf(xv.z, w2, fmaf(xv.w, w3, acc[r]))));
        }
    }

    int lane = t & 63, wid = t >> 6;
    float was = att_s[t], wad = att_d[t];
    #pragma unroll
    for (int r = 0; r < 16; ++r) {
        int row = row0 + r;
        if (row >= N) break;
        hb[(size_t)row * DF + t] = __float2bfloat16(acc[r]);
        float vs = acc[r] * was, vd = acc[r] * wad;
        #pragma unroll
        for (int m = 32; m >= 1; m >>= 1) {
            vs += __shfl_xor(vs, m, 64);
            vd += __shfl_xor(vd, m, 64);
        }
        if (lane == 0) { a_s[row * 4 + wid] = vs; a_d[row * 4 + wid] = vd; }
    }
}

// ---------------- K2: in-degree histogram ----------------
__global__ void k_count(const int* __restrict__ dste, int E, int* __restrict__ indeg)
{
    for (int e = blockIdx.x * blockDim.x + threadIdx.x; e < E; e += gridDim.x * blockDim.x)
        atomicAdd(&indeg[dste[e]], 1);
}

// ---------------- K3a: per-1024-block partial sums ----------------
__global__ __launch_bounds__(256) void k_scanA(const int* __restrict__ indeg, int N, int* __restrict__ part)
{
    int t = threadIdx.x, base = blockIdx.x * 1024;
    int s = 0;
    #pragma unroll
    for (int j = 0; j < 4; ++j) { int i = base + t * 4 + j; if (i < N) s += indeg[i]; }
    #pragma unroll
    for (int m = 32; m >= 1; m >>= 1) s += __shfl_xor(s, m, 64);
    __shared__ int red[4];
    if ((t & 63) == 0) red[t >> 6] = s;
    __syncthreads();
    if (t == 0) part[blockIdx.x] = red[0] + red[1] + red[2] + red[3];
}

// ---------------- K3b: exclusive scan of block partials (NB <= 128) ----------------
__global__ __launch_bounds__(128) void k_scanB(const int* __restrict__ part, int NB, int* __restrict__ bloff)
{
    __shared__ int buf[128];
    int t = threadIdx.x;
    int v = (t < NB) ? part[t] : 0;
    buf[t] = v;
    __syncthreads();
    for (int off = 1; off < 128; off <<= 1) {
        int x2 = (t >= off) ? buf[t - off] : 0;
        __syncthreads();
        buf[t] += x2;
        __syncthreads();
    }
    if (t < NB) bloff[t] = buf[t] - v;   // exclusive
}

// ---------------- K3c: final exclusive scan -> offsets + cursor ----------------
__global__ __launch_bounds__(256) void k_scanC(const int* __restrict__ indeg, int N,
        const int* __restrict__ bloff, int* __restrict__ offs, int* __restrict__ cur)
{
    int t = threadIdx.x, bid = blockIdx.x, base = bid * 1024;
    int v[4]; int s = 0;
    #pragma unroll
    for (int j = 0; j < 4; ++j) { int i = base + t * 4 + j; v[j] = (i < N) ? indeg[i] : 0; s += v[j]; }
    __shared__ int lds[256];
    lds[t] = s;
    __syncthreads();
    for (int off = 1; off < 256; off <<= 1) {
        int x2 = (t >= off) ? lds[t - off] : 0;
        __syncthreads();
        lds[t] += x2;
        __syncthreads();
    }
    int run = lds[t] - s + bloff[bid];
    #pragma unroll
    for (int j = 0; j < 4; ++j) {
        int i = base + t * 4 + j;
        if (i < N) { offs[i] = run; cur[i] = run; }
        run += v[j];
    }
    if (bid == (int)gridDim.x - 1 && t == 255) offs[N] = run;  // == E
}

// ---------------- K4: scatter edges into CSR ----------------
__global__ void k_scatter(const int* __restrict__ srce, const int* __restrict__ dste, int E,
                          int* __restrict__ cur, int* __restrict__ srclist)
{
    for (int e = blockIdx.x * blockDim.x + threadIdx.x; e < E; e += gridDim.x * blockDim.x) {
        int d = dste[e];
        int p = atomicAdd(&cur[d], 1);
        srclist[p] = srce[e];
    }
}

// ---------------- K5: per-dst softmax + weighted gather + bias/ELU/LayerNorm ----------------
// one block (256 thr) per destination node; thread t owns output dim t; head = t>>6.
__global__ __launch_bounds__(256) void k_gather(
        const __hip_bfloat16* __restrict__ hb,
        const float* __restrict__ a_s, const float* __restrict__ a_d,
        const int* __restrict__ offs, const int* __restrict__ srclist,
        const float* __restrict__ bias, const float* __restrict__ gamma,
        const float* __restrict__ beta, float* __restrict__ out, int N)
{
    int n = blockIdx.x;
    int t = threadIdx.x;
    int head = t >> 6, lane = t & 63;
    int beg = offs[n], end = offs[n + 1];

    float4 ad4 = ((const float4*)a_d)[n];
    float4 as4 = ((const float4*)a_s)[n];
    float adn[4] = { ad4.x, ad4.y, ad4.z, ad4.w };
    float asn[4] = { as4.x, as4.y, as4.z, as4.w };

    __shared__ float s_den[4];
    if (t < 4) s_den[t] = expf(lrelu(asn[t] + adn[t]));   // self-loop term
    __syncthreads();

    // pass 1: softmax denominators (4 heads), gathers hit L2/L3 (a_s is 1.6 MB)
    float dl0 = 0.f, dl1 = 0.f, dl2 = 0.f, dl3 = 0.f;
    for (int e = beg + t; e < end; e += 256) {
        int s = srclist[e];
        float4 av = ((const float4*)a_s)[s];
        dl0 += expf(lrelu(av.x + adn[0]));
        dl1 += expf(lrelu(av.y + adn[1]));
        dl2 += expf(lrelu(av.z + adn[2]));
        dl3 += expf(lrelu(av.w + adn[3]));
    }
    #pragma unroll
    for (int m = 32; m >= 1; m >>= 1) {
        dl0 += __shfl_xor(dl0, m, 64);
        dl1 += __shfl_xor(dl1, m, 64);
        dl2 += __shfl_xor(dl2, m, 64);
        dl3 += __shfl_xor(dl3, m, 64);
    }
    if (lane == 0) {
        atomicAdd(&s_den[0], dl0); atomicAdd(&s_den[1], dl1);
        atomicAdd(&s_den[2], dl2); atomicAdd(&s_den[3], dl3);
    }
    __syncthreads();

    float inv_hh = 1.f / s_den[t & 3];         // for alpha tile computation
    float inv_h  = 1.f / s_den[head];          // for this thread's accumulation

    // self-loop contribution
    float acc = __bfloat162float(hb[(size_t)n * DF + t]) *
                (expf(lrelu(asn[head] + adn[head])) * inv_h);

    __shared__ int   s_src[64];
    __shared__ float s_alpha[64 * 4];
    for (int tb = beg; tb < end; tb += 64) {
        int m = end - tb; if (m > 64) m = 64;
        int eix = t >> 2, hh = t & 3;
        if (eix < m) {
            int s = srclist[tb + eix];
            if (hh == 0) s_src[eix] = s;
            float av = a_s[s * 4 + hh];
            s_alpha[eix * 4 + hh] = expf(lrelu(av + adn[hh])) * inv_hh;
        }
        __syncthreads();
        for (int j = 0; j < m; ++j) {
            float hv = __bfloat162float(hb[(size_t)s_src[j] * DF + t]);
            acc = fmaf(s_alpha[j * 4 + head], hv, acc);
        }
        __syncthreads();
    }

    // epilogue: bias + ELU + LayerNorm over 256 dims
    float v = acc + bias[t];
    v = v > 0.f ? v : expm1f(v);

    float s1 = v, s2 = v * v;
    #pragma unroll
    for (int m = 32; m >= 1; m >>= 1) {
        s1 += __shfl_xor(s1, m, 64);
        s2 += __shfl_xor(s2, m, 64);
    }
    __shared__ float r1[4], r2[4];
    if (lane == 0) { r1[head] = s1; r2[head] = s2; }
    __syncthreads();
    float S1 = r1[0] + r1[1] + r1[2] + r1[3];
    float S2 = r2[0] + r2[1] + r2[2] + r2[3];
    float mu = S1 * (1.f / 256.f);
    float var = S2 * (1.f / 256.f) - mu * mu;
    float y = (v - mu) * rsqrtf(var + LN_EPS) * gamma[t] + beta[t];
    out[(size_t)n * DF + t] = y;
}

extern "C" void kernel_launch(void* const* d_in, const int* in_sizes, int n_in,
                              void* d_out, int out_size, void* d_ws, size_t ws_size,
                              hipStream_t stream)
{
    const float* x     = (const float*)d_in[0];
    const int*   ei    = (const int*)d_in[1];
    const float* W     = (const float*)d_in[2];
    const float* att_s = (const float*)d_in[3];
    const float* att_d = (const float*)d_in[4];
    const float* bias  = (const float*)d_in[5];
    const float* gamma = (const float*)d_in[6];
    const float* beta  = (const float*)d_in[7];
    float* out = (float*)d_out;

    int N = in_sizes[0] / IN_F;
    int E = in_sizes[1] / 2;
    const int* srce = ei;
    const int* dste = ei + E;

    char* wsb = (char*)d_ws;
    size_t off = 0;
    auto alloc = [&](size_t bytes) -> void* {
        void* p = wsb + off;
        off += (bytes + 255) & ~(size_t)255;
        return p;
    };
    __hip_bfloat16* hb = (__hip_bfloat16*)alloc((size_t)N * DF * sizeof(__hip_bfloat16));
    float* a_s   = (float*)alloc((size_t)N * 4 * sizeof(float));
    float* a_d   = (float*)alloc((size_t)N * 4 * sizeof(float));
    int*   indeg = (int*)alloc((size_t)N * sizeof(int));
    int*   offs  = (int*)alloc(((size_t)N + 1) * sizeof(int));
    int*   cur   = (int*)alloc((size_t)N * sizeof(int));
    int*   srclist = (int*)alloc((size_t)E * sizeof(int));
    int NB = (N + 1023) / 1024;
    int* part  = (int*)alloc((size_t)NB * sizeof(int));
    int* bloff = (int*)alloc((size_t)NB * sizeof(int));

    hipMemsetAsync(indeg, 0, (size_t)N * sizeof(int), stream);

    k_gemm<<<(N + 15) / 16, 256, 0, stream>>>(x, W, att_s, att_d, hb, a_s, a_d, N);
    k_count<<<2048, 256, 0, stream>>>(dste, E, indeg);
    k_scanA<<<NB, 256, 0, stream>>>(indeg, N, part);
    k_scanB<<<1, 128, 0, stream>>>(part, NB, bloff);
    k_scanC<<<NB, 256, 0, stream>>>(indeg, N, bloff, offs, cur);
    k_scatter<<<2048, 256, 0, stream>>>(srce, dste, E, cur, srclist);
    k_gather<<<N, 256, 0, stream>>>(hb, a_s, a_d, offs, srclist, bias, gamma, beta, out, N);
}

// Round 4
// 639.479 us; speedup vs baseline: 1.2652x; 1.2652x over previous
//
#include <hip/hip_runtime.h>
#include <hip/hip_bf16.h>

#define IN_F 128
#define DF   256
#define HEADS 4
#define CPH  64
#define NEG  0.2f
#define LN_EPS 1e-5f

__device__ __forceinline__ float lrelu(float x) { return x > 0.f ? x : NEG * x; }
__device__ __forceinline__ float b2f(unsigned short u) {
    union { unsigned int i; float f; } v; v.i = ((unsigned int)u) << 16; return v.f;
}

// ---------------- K1: h = x @ W  (store bf16), fused a_s/a_d ----------------
__global__ __launch_bounds__(256) void k_gemm(
        const float* __restrict__ x, const float* __restrict__ W,
        const float* __restrict__ att_s, const float* __restrict__ att_d,
        __hip_bfloat16* __restrict__ hb,
        float* __restrict__ a_s, float* __restrict__ a_d, int N)
{
    __shared__ float xs[16 * IN_F];
    int t = threadIdx.x;
    int row0 = blockIdx.x * 16;

    const float4* xg = (const float4*)(x + (size_t)row0 * IN_F);
    float4* xs4 = (float4*)xs;
    #pragma unroll
    for (int j = 0; j < 2; ++j) {
        int s = t + j * 256;
        if (row0 + (s >> 5) < N) xs4[s] = xg[s];
        else xs4[s] = make_float4(0.f, 0.f, 0.f, 0.f);
    }
    __syncthreads();

    float acc[16];
    #pragma unroll
    for (int r = 0; r < 16; ++r) acc[r] = 0.f;

    const float* Wc = W + t;
    for (int k0 = 0; k0 < IN_F; k0 += 4) {
        float w0 = Wc[(k0 + 0) * DF];
        float w1 = Wc[(k0 + 1) * DF];
        float w2 = Wc[(k0 + 2) * DF];
        float w3 = Wc[(k0 + 3) * DF];
        #pragma unroll
        for (int r = 0; r < 16; ++r) {
            float4 xv = xs4[r * 32 + (k0 >> 2)];
            acc[r] = fmaf(xv.x, w0, fmaf(xv.y, w1, fmaf(xv.z, w2, fmaf(xv.w, w3, acc[r]))));
        }
    }

    int lane = t & 63, wid = t >> 6;
    float was = att_s[t], wad = att_d[t];
    #pragma unroll
    for (int r = 0; r < 16; ++r) {
        int row = row0 + r;
        if (row >= N) break;
        hb[(size_t)row * DF + t] = __float2bfloat16(acc[r]);
        float vs = acc[r] * was, vd = acc[r] * wad;
        #pragma unroll
        for (int m = 32; m >= 1; m >>= 1) {
            vs += __shfl_xor(vs, m, 64);
            vd += __shfl_xor(vd, m, 64);
        }
        if (lane == 0) { a_s[row * 4 + wid] = vs; a_d[row * 4 + wid] = vd; }
    }
}

// ---------------- K2: in-degree histogram ----------------
__global__ void k_count(const int* __restrict__ dste, int E, int* __restrict__ indeg)
{
    for (int e = blockIdx.x * blockDim.x + threadIdx.x; e < E; e += gridDim.x * blockDim.x)
        atomicAdd(&indeg[dste[e]], 1);
}

// ---------------- K3a: per-1024-block partial sums ----------------
__global__ __launch_bounds__(256) void k_scanA(const int* __restrict__ indeg, int N, int* __restrict__ part)
{
    int t = threadIdx.x, base = blockIdx.x * 1024;
    int s = 0;
    #pragma unroll
    for (int j = 0; j < 4; ++j) { int i = base + t * 4 + j; if (i < N) s += indeg[i]; }
    #pragma unroll
    for (int m = 32; m >= 1; m >>= 1) s += __shfl_xor(s, m, 64);
    __shared__ int red[4];
    if ((t & 63) == 0) red[t >> 6] = s;
    __syncthreads();
    if (t == 0) part[blockIdx.x] = red[0] + red[1] + red[2] + red[3];
}

// ---------------- K3b: exclusive scan of block partials (NB <= 128) ----------------
__global__ __launch_bounds__(128) void k_scanB(const int* __restrict__ part, int NB, int* __restrict__ bloff)
{
    __shared__ int buf[128];
    int t = threadIdx.x;
    int v = (t < NB) ? part[t] : 0;
    buf[t] = v;
    __syncthreads();
    for (int off = 1; off < 128; off <<= 1) {
        int x2 = (t >= off) ? buf[t - off] : 0;
        __syncthreads();
        buf[t] += x2;
        __syncthreads();
    }
    if (t < NB) bloff[t] = buf[t] - v;   // exclusive
}

// ---------------- K3c: final exclusive scan -> offsets + cursor ----------------
__global__ __launch_bounds__(256) void k_scanC(const int* __restrict__ indeg, int N,
        const int* __restrict__ bloff, int* __restrict__ offs, int* __restrict__ cur)
{
    int t = threadIdx.x, bid = blockIdx.x, base = bid * 1024;
    int v[4]; int s = 0;
    #pragma unroll
    for (int j = 0; j < 4; ++j) { int i = base + t * 4 + j; v[j] = (i < N) ? indeg[i] : 0; s += v[j]; }
    __shared__ int lds[256];
    lds[t] = s;
    __syncthreads();
    for (int off = 1; off < 256; off <<= 1) {
        int x2 = (t >= off) ? lds[t - off] : 0;
        __syncthreads();
        lds[t] += x2;
        __syncthreads();
    }
    int run = lds[t] - s + bloff[bid];
    #pragma unroll
    for (int j = 0; j < 4; ++j) {
        int i = base + t * 4 + j;
        if (i < N) { offs[i] = run; cur[i] = run; }
        run += v[j];
    }
    if (bid == (int)gridDim.x - 1 && t == 255) offs[N] = run;  // == E
}

// ---------------- K4: scatter edges into CSR ----------------
__global__ void k_scatter(const int* __restrict__ srce, const int* __restrict__ dste, int E,
                          int* __restrict__ cur, int* __restrict__ srclist)
{
    for (int e = blockIdx.x * blockDim.x + threadIdx.x; e < E; e += gridDim.x * blockDim.x) {
        int d = dste[e];
        int p = atomicAdd(&cur[d], 1);
        srclist[p] = srce[e];
    }
}

// ---------------- K5: wave-per-node fused softmax+gather+bias/ELU/LayerNorm ----------------
// One 64-lane wave per destination node (4 nodes per 256-thr block).
// Lane l owns dims [4l, 4l+3]; head = l>>4. Single pass: accumulate
// unnormalized sum(p * h[src]) and den = sum(p); scale at the end.
// No LDS, no __syncthreads.
__global__ __launch_bounds__(256) void k_gather(
        const __hip_bfloat16* __restrict__ hb,
        const float* __restrict__ a_s, const float* __restrict__ a_d,
        const int* __restrict__ offs, const int* __restrict__ srclist,
        const float* __restrict__ bias, const float* __restrict__ gamma,
        const float* __restrict__ beta, float* __restrict__ out, int N)
{
    int wid = threadIdx.x >> 6, lane = threadIdx.x & 63;
    int n = blockIdx.x * 4 + wid;
    if (n >= N) return;
    int head = lane >> 4;
    int d0 = lane << 2;

    float adh = a_d[(size_t)n * 4 + head];
    int beg = offs[n], end = offs[n + 1];

    // self-loop term
    float acc0, acc1, acc2, acc3, den;
    {
        float as = a_s[(size_t)n * 4 + head];
        float p = expf(lrelu(as + adh));
        den = p;
        ushort4 hv = *(const ushort4*)(hb + (size_t)n * DF + d0);
        acc0 = p * b2f(hv.x); acc1 = p * b2f(hv.y);
        acc2 = p * b2f(hv.z); acc3 = p * b2f(hv.w);
    }

    // edges: whole wave on one edge's 256 dims; prefetch next src index
    int e = beg;
    int s_next = (e < end) ? srclist[e] : 0;
    while (e < end) {
        int s = s_next;
        ++e;
        if (e < end) s_next = srclist[e];
        float as = a_s[(size_t)s * 4 + head];
        ushort4 hv = *(const ushort4*)(hb + (size_t)s * DF + d0);
        float p = expf(lrelu(as + adh));
        den += p;
        acc0 = fmaf(p, b2f(hv.x), acc0); acc1 = fmaf(p, b2f(hv.y), acc1);
        acc2 = fmaf(p, b2f(hv.z), acc2); acc3 = fmaf(p, b2f(hv.w), acc3);
    }

    float inv = 1.f / den;
    float4 bia = *(const float4*)(bias + d0);
    float v0 = fmaf(acc0, inv, bia.x);
    float v1 = fmaf(acc1, inv, bia.y);
    float v2 = fmaf(acc2, inv, bia.z);
    float v3 = fmaf(acc3, inv, bia.w);
    v0 = v0 > 0.f ? v0 : expm1f(v0);
    v1 = v1 > 0.f ? v1 : expm1f(v1);
    v2 = v2 > 0.f ? v2 : expm1f(v2);
    v3 = v3 > 0.f ? v3 : expm1f(v3);

    float s1 = v0 + v1 + v2 + v3;
    float s2 = v0 * v0 + v1 * v1 + v2 * v2 + v3 * v3;
    #pragma unroll
    for (int m = 32; m >= 1; m >>= 1) {
        s1 += __shfl_xor(s1, m, 64);
        s2 += __shfl_xor(s2, m, 64);
    }
    float mu = s1 * (1.f / 256.f);
    float var = s2 * (1.f / 256.f) - mu * mu;
    float rs = rsqrtf(var + LN_EPS);
    float4 g  = *(const float4*)(gamma + d0);
    float4 be = *(const float4*)(beta + d0);
    float4 o;
    o.x = (v0 - mu) * rs * g.x + be.x;
    o.y = (v1 - mu) * rs * g.y + be.y;
    o.z = (v2 - mu) * rs * g.z + be.z;
    o.w = (v3 - mu) * rs * g.w + be.w;
    *(float4*)(out + (size_t)n * DF + d0) = o;
}

extern "C" void kernel_launch(void* const* d_in, const int* in_sizes, int n_in,
                              void* d_out, int out_size, void* d_ws, size_t ws_size,
                              hipStream_t stream)
{
    const float* x     = (const float*)d_in[0];
    const int*   ei    = (const int*)d_in[1];
    const float* W     = (const float*)d_in[2];
    const float* att_s = (const float*)d_in[3];
    const float* att_d = (const float*)d_in[4];
    const float* bias  = (const float*)d_in[5];
    const float* gamma = (const float*)d_in[6];
    const float* beta  = (const float*)d_in[7];
    float* out = (float*)d_out;

    int N = in_sizes[0] / IN_F;
    int E = in_sizes[1] / 2;
    const int* srce = ei;
    const int* dste = ei + E;

    char* wsb = (char*)d_ws;
    size_t off = 0;
    auto alloc = [&](size_t bytes) -> void* {
        void* p = wsb + off;
        off += (bytes + 255) & ~(size_t)255;
        return p;
    };
    __hip_bfloat16* hb = (__hip_bfloat16*)alloc((size_t)N * DF * sizeof(__hip_bfloat16));
    float* a_s   = (float*)alloc((size_t)N * 4 * sizeof(float));
    float* a_d   = (float*)alloc((size_t)N * 4 * sizeof(float));
    int*   indeg = (int*)alloc((size_t)N * sizeof(int));
    int*   offs  = (int*)alloc(((size_t)N + 1) * sizeof(int));
    int*   cur   = (int*)alloc((size_t)N * sizeof(int));
    int*   srclist = (int*)alloc((size_t)E * sizeof(int));
    int NB = (N + 1023) / 1024;
    int* part  = (int*)alloc((size_t)NB * sizeof(int));
    int* bloff = (int*)alloc((size_t)NB * sizeof(int));

    hipMemsetAsync(indeg, 0, (size_t)N * sizeof(int), stream);

    k_gemm<<<(N + 15) / 16, 256, 0, stream>>>(x, W, att_s, att_d, hb, a_s, a_d, N);
    k_count<<<2048, 256, 0, stream>>>(dste, E, indeg);
    k_scanA<<<NB, 256, 0, stream>>>(indeg, N, part);
    k_scanB<<<1, 128, 0, stream>>>(part, NB, bloff);
    k_scanC<<<NB, 256, 0, stream>>>(indeg, N, bloff, offs, cur);
    k_scatter<<<2048, 256, 0, stream>>>(srce, dste, E, cur, srclist);
    k_gather<<<(N + 3) / 4, 256, 0, stream>>>(hb, a_s, a_d, offs, srclist, bias, gamma, beta, out, N);
}

// Round 6
// 527.038 us; speedup vs baseline: 1.5351x; 1.2133x over previous
//
#include <hip/hip_runtime.h>
#include <hip/hip_bf16.h>

#define IN_F 128
#define DF   256
#define NEG  0.2f
#define LN_EPS 1e-5f

typedef __attribute__((ext_vector_type(8))) short bf16x8;
typedef __attribute__((ext_vector_type(4))) float f32x4;

__device__ __forceinline__ float lrelu(float x) { return x > 0.f ? x : NEG * x; }
__device__ __forceinline__ float b2f(unsigned short u) {
    union { unsigned int i; float f; } v; v.i = ((unsigned int)u) << 16; return v.f;
}
// f32 -> bf16 with round-to-nearest-even (finite inputs)
__device__ __forceinline__ unsigned short f2b(float f) {
    union { float f; unsigned int i; } v; v.f = f;
    unsigned int r = v.i + 0x7FFFu + ((v.i >> 16) & 1u);
    return (unsigned short)(r >> 16);
}

// ---------------- K0: pack W (f32 row-major 128x256) into bf16 B-fragment layout ----
// Wp[((ct*4 + ks)*64 + lane)*8 + j] = bf16(W[k][col]), col = ct*16 + (lane&15),
// k = ks*32 + (lane>>4)*8 + j.   16 col-tiles, 4 k-steps, 64 lanes, 8 elems.
__global__ __launch_bounds__(256) void k_pack(const float* __restrict__ W,
                                              unsigned short* __restrict__ Wp)
{
    int t = blockIdx.x * 256 + threadIdx.x;     // 4096 threads
    if (t >= 16 * 4 * 64) return;
    int lane = t & 63, ks = (t >> 6) & 3, ct = t >> 8;
    int col = ct * 16 + (lane & 15);
    int kb  = ks * 32 + (lane >> 4) * 8;
    unsigned short* dst = Wp + (size_t)t * 8;
    #pragma unroll
    for (int j = 0; j < 8; ++j)
        dst[j] = f2b(W[(size_t)(kb + j) * DF + col]);
}

// ---------------- K1: h = x @ W via bf16 MFMA (store bf16) ----------------
// Block: 256 thr = 4 waves (2x2). Tile 64 rows x 256 cols, K = 128 (one shot).
#define APAD 136   // LDS row stride in bf16 elems (128 + 8 pad) = 272 B
__global__ __launch_bounds__(256) void k_gemm(
        const float* __restrict__ x, const unsigned short* __restrict__ Wp,
        unsigned short* __restrict__ hb, int N)
{
    __shared__ unsigned short lds_a[64 * APAD];
    int t = threadIdx.x;
    int row0 = blockIdx.x * 64;

    // stage x tile (64 x 128 f32) -> bf16 LDS, padded rows
    const float4* xg = (const float4*)x;
    #pragma unroll
    for (int j = 0; j < 8; ++j) {
        int s = t + j * 256;            // 2048 float4 slots = 64 rows x 32
        int r = s >> 5, c4 = s & 31;
        ushort4 w = make_ushort4(0, 0, 0, 0);
        if (row0 + r < N) {
            float4 xv = xg[(size_t)(row0 + r) * 32 + c4];
            w = make_ushort4(f2b(xv.x), f2b(xv.y), f2b(xv.z), f2b(xv.w));
        }
        *(ushort4*)(&lds_a[r * APAD + c4 * 4]) = w;
    }
    __syncthreads();

    int lane = t & 63, wid = t >> 6;
    int rbase = (wid & 1) * 32;          // local row base for this wave
    int cbase = (wid >> 1) * 128;        // col base
    int ct0 = cbase >> 4;                // first col-tile index (global)

    // preload A fragments: 2 row-tiles x 4 k-steps
    bf16x8 af[2][4];
    #pragma unroll
    for (int rt = 0; rt < 2; ++rt)
        #pragma unroll
        for (int ks = 0; ks < 4; ++ks) {
            int r = rbase + rt * 16 + (lane & 15);
            int k = ks * 32 + (lane >> 4) * 8;
            af[rt][ks] = *(const bf16x8*)(&lds_a[r * APAD + k]);
        }

    f32x4 acc[2][8];
    #pragma unroll
    for (int rt = 0; rt < 2; ++rt)
        #pragma unroll
        for (int ct = 0; ct < 8; ++ct)
            acc[rt][ct] = (f32x4){0.f, 0.f, 0.f, 0.f};

    const bf16x8* Wp8 = (const bf16x8*)Wp;
    #pragma unroll
    for (int ct = 0; ct < 8; ++ct) {
        #pragma unroll
        for (int ks = 0; ks < 4; ++ks) {
            bf16x8 b = Wp8[((ct0 + ct) * 4 + ks) * 64 + lane];
            acc[0][ct] = __builtin_amdgcn_mfma_f32_16x16x32_bf16(af[0][ks], b, acc[0][ct], 0, 0, 0);
            acc[1][ct] = __builtin_amdgcn_mfma_f32_16x16x32_bf16(af[1][ks], b, acc[1][ct], 0, 0, 0);
        }
    }

    // store: C/D layout col = lane&15, row = (lane>>4)*4 + r
    #pragma unroll
    for (int rt = 0; rt < 2; ++rt) {
        #pragma unroll
        for (int ct = 0; ct < 8; ++ct) {
            int col = cbase + ct * 16 + (lane & 15);
            #pragma unroll
            for (int r = 0; r < 4; ++r) {
                int row = row0 + rbase + rt * 16 + (lane >> 4) * 4 + r;
                if (row < N)
                    hb[(size_t)row * DF + col] = f2b(acc[rt][ct][r]);
            }
        }
    }
}

// ---------------- K1b: a_s/a_d from hb ----------------
__global__ __launch_bounds__(256) void k_att(
        const unsigned short* __restrict__ hb,
        const float* __restrict__ att_s, const float* __restrict__ att_d,
        float* __restrict__ a_s, float* __restrict__ a_d, int N)
{
    int wid = threadIdx.x >> 6, lane = threadIdx.x & 63;
    int n = blockIdx.x * 4 + wid;
    if (n >= N) return;
    int d0 = lane << 2, head = lane >> 4;
    ushort4 hv = *(const ushort4*)(hb + (size_t)n * DF + d0);
    float4 as4 = *(const float4*)(att_s + d0);
    float4 ad4 = *(const float4*)(att_d + d0);
    float h0 = b2f(hv.x), h1 = b2f(hv.y), h2 = b2f(hv.z), h3 = b2f(hv.w);
    float vs = h0 * as4.x + h1 * as4.y + h2 * as4.z + h3 * as4.w;
    float vd = h0 * ad4.x + h1 * ad4.y + h2 * ad4.z + h3 * ad4.w;
    #pragma unroll
    for (int m = 8; m >= 1; m >>= 1) {
        vs += __shfl_xor(vs, m, 64);
        vd += __shfl_xor(vd, m, 64);
    }
    if ((lane & 15) == 0) {
        a_s[(size_t)n * 4 + head] = vs;
        a_d[(size_t)n * 4 + head] = vd;
    }
}

// ---------------- K2: in-degree histogram ----------------
__global__ void k_count(const int* __restrict__ dste, int E, int* __restrict__ indeg)
{
    for (int e = blockIdx.x * blockDim.x + threadIdx.x; e < E; e += gridDim.x * blockDim.x)
        atomicAdd(&indeg[dste[e]], 1);
}

// ---------------- K3a: per-1024-block partial sums ----------------
__global__ __launch_bounds__(256) void k_scanA(const int* __restrict__ indeg, int N, int* __restrict__ part)
{
    int t = threadIdx.x, base = blockIdx.x * 1024;
    int s = 0;
    #pragma unroll
    for (int j = 0; j < 4; ++j) { int i = base + t * 4 + j; if (i < N) s += indeg[i]; }
    #pragma unroll
    for (int m = 32; m >= 1; m >>= 1) s += __shfl_xor(s, m, 64);
    __shared__ int red[4];
    if ((t & 63) == 0) red[t >> 6] = s;
    __syncthreads();
    if (t == 0) part[blockIdx.x] = red[0] + red[1] + red[2] + red[3];
}

// ---------------- K3b: exclusive scan of block partials (NB <= 128) ----------------
__global__ __launch_bounds__(128) void k_scanB(const int* __restrict__ part, int NB, int* __restrict__ bloff)
{
    __shared__ int buf[128];
    int t = threadIdx.x;
    int v = (t < NB) ? part[t] : 0;
    buf[t] = v;
    __syncthreads();
    for (int off = 1; off < 128; off <<= 1) {
        int x2 = (t >= off) ? buf[t - off] : 0;
        __syncthreads();
        buf[t] += x2;
        __syncthreads();
    }
    if (t < NB) bloff[t] = buf[t] - v;   // exclusive
}

// ---------------- K3c: final exclusive scan -> offsets + cursor ----------------
__global__ __launch_bounds__(256) void k_scanC(const int* __restrict__ indeg, int N,
        const int* __restrict__ bloff, int* __restrict__ offs, int* __restrict__ cur)
{
    int t = threadIdx.x, bid = blockIdx.x, base = bid * 1024;
    int v[4]; int s = 0;
    #pragma unroll
    for (int j = 0; j < 4; ++j) { int i = base + t * 4 + j; v[j] = (i < N) ? indeg[i] : 0; s += v[j]; }
    __shared__ int lds[256];
    lds[t] = s;
    __syncthreads();
    for (int off = 1; off < 256; off <<= 1) {
        int x2 = (t >= off) ? lds[t - off] : 0;
        __syncthreads();
        lds[t] += x2;
        __syncthreads();
    }
    int run = lds[t] - s + bloff[bid];
    #pragma unroll
    for (int j = 0; j < 4; ++j) {
        int i = base + t * 4 + j;
        if (i < N) { offs[i] = run; cur[i] = run; }
        run += v[j];
    }
    if (bid == (int)gridDim.x - 1 && t == 255) offs[N] = run;  // == E
}

// ---------------- K4: scatter edges into CSR ----------------
__global__ void k_scatter(const int* __restrict__ srce, const int* __restrict__ dste, int E,
                          int* __restrict__ cur, int* __restrict__ srclist)
{
    for (int e = blockIdx.x * blockDim.x + threadIdx.x; e < E; e += gridDim.x * blockDim.x) {
        int d = dste[e];
        int p = atomicAdd(&cur[d], 1);
        srclist[p] = srce[e];
    }
}

// ---------------- K5: wave-per-node fused softmax+gather+bias/ELU/LayerNorm ----------------
__global__ __launch_bounds__(256) void k_gather(
        const unsigned short* __restrict__ hb,
        const float* __restrict__ a_s, const float* __restrict__ a_d,
        const int* __restrict__ offs, const int* __restrict__ srclist,
        const float* __restrict__ bias, const float* __restrict__ gamma,
        const float* __restrict__ beta, float* __restrict__ out, int N)
{
    int wid = threadIdx.x >> 6, lane = threadIdx.x & 63;
    int n = blockIdx.x * 4 + wid;
    if (n >= N) return;
    int head = lane >> 4;
    int d0 = lane << 2;

    float adh = a_d[(size_t)n * 4 + head];
    int beg = offs[n], end = offs[n + 1];

    // self-loop term
    float acc0, acc1, acc2, acc3, den;
    {
        float as = a_s[(size_t)n * 4 + head];
        float p = expf(lrelu(as + adh));
        den = p;
        ushort4 hv = *(const ushort4*)(hb + (size_t)n * DF + d0);
        acc0 = p * b2f(hv.x); acc1 = p * b2f(hv.y);
        acc2 = p * b2f(hv.z); acc3 = p * b2f(hv.w);
    }

    int e = beg;
    int s_next = (e < end) ? srclist[e] : 0;
    while (e < end) {
        int s = s_next;
        ++e;
        if (e < end) s_next = srclist[e];
        float as = a_s[(size_t)s * 4 + head];
        ushort4 hv = *(const ushort4*)(hb + (size_t)s * DF + d0);
        float p = expf(lrelu(as + adh));
        den += p;
        acc0 = fmaf(p, b2f(hv.x), acc0); acc1 = fmaf(p, b2f(hv.y), acc1);
        acc2 = fmaf(p, b2f(hv.z), acc2); acc3 = fmaf(p, b2f(hv.w), acc3);
    }

    float inv = 1.f / den;
    float4 bia = *(const float4*)(bias + d0);
    float v0 = fmaf(acc0, inv, bia.x);
    float v1 = fmaf(acc1, inv, bia.y);
    float v2 = fmaf(acc2, inv, bia.z);
    float v3 = fmaf(acc3, inv, bia.w);
    v0 = v0 > 0.f ? v0 : expm1f(v0);
    v1 = v1 > 0.f ? v1 : expm1f(v1);
    v2 = v2 > 0.f ? v2 : expm1f(v2);
    v3 = v3 > 0.f ? v3 : expm1f(v3);

    float s1 = v0 + v1 + v2 + v3;
    float s2 = v0 * v0 + v1 * v1 + v2 * v2 + v3 * v3;
    #pragma unroll
    for (int m = 32; m >= 1; m >>= 1) {
        s1 += __shfl_xor(s1, m, 64);
        s2 += __shfl_xor(s2, m, 64);
    }
    float mu = s1 * (1.f / 256.f);
    float var = s2 * (1.f / 256.f) - mu * mu;
    float rs = rsqrtf(var + LN_EPS);
    float4 g  = *(const float4*)(gamma + d0);
    float4 be = *(const float4*)(beta + d0);
    float4 o;
    o.x = (v0 - mu) * rs * g.x + be.x;
    o.y = (v1 - mu) * rs * g.y + be.y;
    o.z = (v2 - mu) * rs * g.z + be.z;
    o.w = (v3 - mu) * rs * g.w + be.w;
    *(float4*)(out + (size_t)n * DF + d0) = o;
}

extern "C" void kernel_launch(void* const* d_in, const int* in_sizes, int n_in,
                              void* d_out, int out_size, void* d_ws, size_t ws_size,
                              hipStream_t stream)
{
    const float* x     = (const float*)d_in[0];
    const int*   ei    = (const int*)d_in[1];
    const float* W     = (const float*)d_in[2];
    const float* att_s = (const float*)d_in[3];
    const float* att_d = (const float*)d_in[4];
    const float* bias  = (const float*)d_in[5];
    const float* gamma = (const float*)d_in[6];
    const float* beta  = (const float*)d_in[7];
    float* out = (float*)d_out;

    int N = in_sizes[0] / IN_F;
    int E = in_sizes[1] / 2;
    const int* srce = ei;
    const int* dste = ei + E;

    char* wsb = (char*)d_ws;
    size_t off = 0;
    auto alloc = [&](size_t bytes) -> void* {
        void* p = wsb + off;
        off += (bytes + 255) & ~(size_t)255;
        return p;
    };
    unsigned short* hb = (unsigned short*)alloc((size_t)N * DF * sizeof(unsigned short));
    unsigned short* Wp = (unsigned short*)alloc((size_t)IN_F * DF * sizeof(unsigned short));
    float* a_s   = (float*)alloc((size_t)N * 4 * sizeof(float));
    float* a_d   = (float*)alloc((size_t)N * 4 * sizeof(float));
    int*   indeg = (int*)alloc((size_t)N * sizeof(int));
    int*   offs  = (int*)alloc(((size_t)N + 1) * sizeof(int));
    int*   cur   = (int*)alloc((size_t)N * sizeof(int));
    int*   srclist = (int*)alloc((size_t)E * sizeof(int));
    int NB = (N + 1023) / 1024;
    int* part  = (int*)alloc((size_t)NB * sizeof(int));
    int* bloff = (int*)alloc((size_t)NB * sizeof(int));

    (void)hipMemsetAsync(indeg, 0, (size_t)N * sizeof(int), stream);

    k_pack<<<16, 256, 0, stream>>>(W, Wp);
    k_gemm<<<(N + 63) / 64, 256, 0, stream>>>(x, Wp, hb, N);
    k_att<<<(N + 3) / 4, 256, 0, stream>>>(hb, att_s, att_d, a_s, a_d, N);
    k_count<<<2048, 256, 0, stream>>>(dste, E, indeg);
    k_scanA<<<NB, 256, 0, stream>>>(indeg, N, part);
    k_scanB<<<1, 128, 0, stream>>>(part, NB, bloff);
    k_scanC<<<NB, 256, 0, stream>>>(indeg, N, bloff, offs, cur);
    k_scatter<<<2048, 256, 0, stream>>>(srce, dste, E, cur, srclist);
    k_gather<<<(N + 3) / 4, 256, 0, stream>>>(hb, a_s, a_d, offs, srclist, bias, gamma, beta, out, N);
}

// Round 8
// 526.678 us; speedup vs baseline: 1.5362x; 1.0007x over previous
//
#include <hip/hip_runtime.h>
#include <hip/hip_bf16.h>

#define IN_F 128
#define DF   256
#define NEG  0.2f
#define LN_EPS 1e-5f

typedef __attribute__((ext_vector_type(8))) short bf16x8;
typedef __attribute__((ext_vector_type(4))) float f32x4;
typedef _Float16 f16;
typedef __attribute__((ext_vector_type(4))) _Float16 f16x4;

__device__ __forceinline__ float lrelu(float x) { return x > 0.f ? x : NEG * x; }
// f32 -> bf16 round-to-nearest-even (finite inputs)
__device__ __forceinline__ unsigned short f2b(float f) {
    union { float f; unsigned int i; } v; v.f = f;
    unsigned int r = v.i + 0x7FFFu + ((v.i >> 16) & 1u);
    return (unsigned short)(r >> 16);
}

// ---------------- K0: pack W (f32 row-major 128x256) into bf16 B-fragment layout ----
__global__ __launch_bounds__(256) void k_pack(const float* __restrict__ W,
                                              unsigned short* __restrict__ Wp)
{
    int t = blockIdx.x * 256 + threadIdx.x;     // 4096 threads
    if (t >= 16 * 4 * 64) return;
    int lane = t & 63, ks = (t >> 6) & 3, ct = t >> 8;
    int col = ct * 16 + (lane & 15);
    int kb  = ks * 32 + (lane >> 4) * 8;
    unsigned short* dst = Wp + (size_t)t * 8;
    #pragma unroll
    for (int j = 0; j < 8; ++j)
        dst[j] = f2b(W[(size_t)(kb + j) * DF + col]);
}

// ---------------- K1: h = x @ W via bf16 MFMA (store fp16) ----------------
#define APAD 136   // LDS row stride in bf16 elems (128 + 8 pad) = 272 B
__global__ __launch_bounds__(256) void k_gemm(
        const float* __restrict__ x, const unsigned short* __restrict__ Wp,
        f16* __restrict__ hb, int N)
{
    __shared__ unsigned short lds_a[64 * APAD];
    int t = threadIdx.x;
    int row0 = blockIdx.x * 64;

    const float4* xg = (const float4*)x;
    #pragma unroll
    for (int j = 0; j < 8; ++j) {
        int s = t + j * 256;            // 2048 float4 slots = 64 rows x 32
        int r = s >> 5, c4 = s & 31;
        ushort4 w = make_ushort4(0, 0, 0, 0);
        if (row0 + r < N) {
            float4 xv = xg[(size_t)(row0 + r) * 32 + c4];
            w = make_ushort4(f2b(xv.x), f2b(xv.y), f2b(xv.z), f2b(xv.w));
        }
        *(ushort4*)(&lds_a[r * APAD + c4 * 4]) = w;
    }
    __syncthreads();

    int lane = t & 63, wid = t >> 6;
    int rbase = (wid & 1) * 32;
    int cbase = (wid >> 1) * 128;
    int ct0 = cbase >> 4;

    bf16x8 af[2][4];
    #pragma unroll
    for (int rt = 0; rt < 2; ++rt)
        #pragma unroll
        for (int ks = 0; ks < 4; ++ks) {
            int r = rbase + rt * 16 + (lane & 15);
            int k = ks * 32 + (lane >> 4) * 8;
            af[rt][ks] = *(const bf16x8*)(&lds_a[r * APAD + k]);
        }

    f32x4 acc[2][8];
    #pragma unroll
    for (int rt = 0; rt < 2; ++rt)
        #pragma unroll
        for (int ct = 0; ct < 8; ++ct)
            acc[rt][ct] = (f32x4){0.f, 0.f, 0.f, 0.f};

    const bf16x8* Wp8 = (const bf16x8*)Wp;
    #pragma unroll
    for (int ct = 0; ct < 8; ++ct) {
        #pragma unroll
        for (int ks = 0; ks < 4; ++ks) {
            bf16x8 b = Wp8[((ct0 + ct) * 4 + ks) * 64 + lane];
            acc[0][ct] = __builtin_amdgcn_mfma_f32_16x16x32_bf16(af[0][ks], b, acc[0][ct], 0, 0, 0);
            acc[1][ct] = __builtin_amdgcn_mfma_f32_16x16x32_bf16(af[1][ks], b, acc[1][ct], 0, 0, 0);
        }
    }

    #pragma unroll
    for (int rt = 0; rt < 2; ++rt) {
        #pragma unroll
        for (int ct = 0; ct < 8; ++ct) {
            int col = cbase + ct * 16 + (lane & 15);
            #pragma unroll
            for (int r = 0; r < 4; ++r) {
                int row = row0 + rbase + rt * 16 + (lane >> 4) * 4 + r;
                if (row < N)
                    hb[(size_t)row * DF + col] = (f16)acc[rt][ct][r];
            }
        }
    }
}

// ---------------- K1b: a_s/a_d from hb ----------------
__global__ __launch_bounds__(256) void k_att(
        const f16* __restrict__ hb,
        const float* __restrict__ att_s, const float* __restrict__ att_d,
        float* __restrict__ a_s, float* __restrict__ a_d, int N)
{
    int wid = threadIdx.x >> 6, lane = threadIdx.x & 63;
    int n = blockIdx.x * 4 + wid;
    if (n >= N) return;
    int d0 = lane << 2, head = lane >> 4;
    f16x4 hv = *(const f16x4*)(hb + (size_t)n * DF + d0);
    float4 as4 = *(const float4*)(att_s + d0);
    float4 ad4 = *(const float4*)(att_d + d0);
    float h0 = (float)hv.x, h1 = (float)hv.y, h2 = (float)hv.z, h3 = (float)hv.w;
    float vs = h0 * as4.x + h1 * as4.y + h2 * as4.z + h3 * as4.w;
    float vd = h0 * ad4.x + h1 * ad4.y + h2 * ad4.z + h3 * ad4.w;
    #pragma unroll
    for (int m = 8; m >= 1; m >>= 1) {
        vs += __shfl_xor(vs, m, 64);
        vd += __shfl_xor(vd, m, 64);
    }
    if ((lane & 15) == 0) {
        a_s[(size_t)n * 4 + head] = vs;
        a_d[(size_t)n * 4 + head] = vd;
    }
}

// ---------------- K2: in-degree histogram ----------------
__global__ void k_count(const int* __restrict__ dste, int E, int* __restrict__ indeg)
{
    for (int e = blockIdx.x * blockDim.x + threadIdx.x; e < E; e += gridDim.x * blockDim.x)
        atomicAdd(&indeg[dste[e]], 1);
}

// ---------------- K3a: per-1024-block partial sums ----------------
__global__ __launch_bounds__(256) void k_scanA(const int* __restrict__ indeg, int N, int* __restrict__ part)
{
    int t = threadIdx.x, base = blockIdx.x * 1024;
    int s = 0;
    #pragma unroll
    for (int j = 0; j < 4; ++j) { int i = base + t * 4 + j; if (i < N) s += indeg[i]; }
    #pragma unroll
    for (int m = 32; m >= 1; m >>= 1) s += __shfl_xor(s, m, 64);
    __shared__ int red[4];
    if ((t & 63) == 0) red[t >> 6] = s;
    __syncthreads();
    if (t == 0) part[blockIdx.x] = red[0] + red[1] + red[2] + red[3];
}

// ---------------- K3b: exclusive scan of block partials (NB <= 128) ----------------
__global__ __launch_bounds__(128) void k_scanB(const int* __restrict__ part, int NB, int* __restrict__ bloff)
{
    __shared__ int buf[128];
    int t = threadIdx.x;
    int v = (t < NB) ? part[t] : 0;
    buf[t] = v;
    __syncthreads();
    for (int off = 1; off < 128; off <<= 1) {
        int x2 = (t >= off) ? buf[t - off] : 0;
        __syncthreads();
        buf[t] += x2;
        __syncthreads();
    }
    if (t < NB) bloff[t] = buf[t] - v;   // exclusive
}

// ---------------- K3c: final exclusive scan -> offsets + cursor ----------------
__global__ __launch_bounds__(256) void k_scanC(const int* __restrict__ indeg, int N,
        const int* __restrict__ bloff, int* __restrict__ offs, int* __restrict__ cur)
{
    int t = threadIdx.x, bid = blockIdx.x, base = bid * 1024;
    int v[4]; int s = 0;
    #pragma unroll
    for (int j = 0; j < 4; ++j) { int i = base + t * 4 + j; v[j] = (i < N) ? indeg[i] : 0; s += v[j]; }
    __shared__ int lds[256];
    lds[t] = s;
    __syncthreads();
    for (int off = 1; off < 256; off <<= 1) {
        int x2 = (t >= off) ? lds[t - off] : 0;
        __syncthreads();
        lds[t] += x2;
        __syncthreads();
    }
    int run = lds[t] - s + bloff[bid];
    #pragma unroll
    for (int j = 0; j < 4; ++j) {
        int i = base + t * 4 + j;
        if (i < N) { offs[i] = run; cur[i] = run; }
        run += v[j];
    }
    if (bid == (int)gridDim.x - 1 && t == 255) offs[N] = run;  // == E
}

// ---------------- K4: scatter edges into CSR ----------------
__global__ void k_scatter(const int* __restrict__ srce, const int* __restrict__ dste, int E,
                          int* __restrict__ cur, int* __restrict__ srclist)
{
    for (int e = blockIdx.x * blockDim.x + threadIdx.x; e < E; e += gridDim.x * blockDim.x) {
        int d = dste[e];
        int p = atomicAdd(&cur[d], 1);
        srclist[p] = srce[e];
    }
}

// ---------------- K5: wave-per-node fused softmax+gather+bias/ELU/LayerNorm ----------------
// Wave = one dst node. lane = (head = lane>>4, j16 = lane&15); lane owns dims 4*lane..+3.
// Phase A per 16-edge block: lane (j16,head) computes p(edge j16, head) once.
// Phase B: broadcast s_j (shfl, uniform) + p_j (shfl per-head) and FMA the fp16 row.
__global__ __launch_bounds__(256) void k_gather(
        const f16* __restrict__ hb,
        const float* __restrict__ a_s, const float* __restrict__ a_d,
        const int* __restrict__ offs, const int* __restrict__ srclist,
        const float* __restrict__ bias, const float* __restrict__ gamma,
        const float* __restrict__ beta, float* __restrict__ out, int N)
{
    int wid = threadIdx.x >> 6, lane = threadIdx.x & 63;
    int n = blockIdx.x * 4 + wid;
    if (n >= N) return;
    int head = lane >> 4;
    int j16  = lane & 15;
    int d0 = lane << 2;

    float adh = a_d[(size_t)n * 4 + head];
    int beg = offs[n], end = offs[n + 1];

    float acc0, acc1, acc2, acc3;
    float den = 0.f;              // per-lane partial; column j16 of this head
    {   // self-loop
        float as = a_s[(size_t)n * 4 + head];
        float p = __expf(lrelu(as + adh));
        if (j16 == 0) den = p;
        f16x4 hv = *(const f16x4*)(hb + (size_t)n * DF + d0);
        acc0 = p * (float)hv.x; acc1 = p * (float)hv.y;
        acc2 = p * (float)hv.z; acc3 = p * (float)hv.w;
    }

    for (int tb = beg; tb < end; tb += 16) {
        int nb = end - tb; nb = nb > 16 ? 16 : nb;
        int   s = (j16 < nb) ? srclist[tb + j16] : 0;
        float as = a_s[(size_t)s * 4 + head];
        float p  = (j16 < nb) ? __expf(lrelu(as + adh)) : 0.f;
        den += p;
        #pragma unroll 2
        for (int j = 0; j < nb; ++j) {
            int   sj = __shfl(s, j, 64);                     // uniform -> readlane
            float pj = __shfl(p, (lane & 0x30) | j, 64);     // per-head broadcast
            f16x4 hv = *(const f16x4*)(hb + (size_t)sj * DF + d0);
            acc0 = fmaf(pj, (float)hv.x, acc0);
            acc1 = fmaf(pj, (float)hv.y, acc1);
            acc2 = fmaf(pj, (float)hv.z, acc2);
            acc3 = fmaf(pj, (float)hv.w, acc3);
        }
    }

    // den: sum the 16 per-column partials within each head group
    #pragma unroll
    for (int m = 8; m >= 1; m >>= 1) den += __shfl_xor(den, m, 64);

    float inv = 1.f / den;
    float4 bia = *(const float4*)(bias + d0);
    float v0 = fmaf(acc0, inv, bia.x);
    float v1 = fmaf(acc1, inv, bia.y);
    float v2 = fmaf(acc2, inv, bia.z);
    float v3 = fmaf(acc3, inv, bia.w);
    v0 = v0 > 0.f ? v0 : expm1f(v0);
    v1 = v1 > 0.f ? v1 : expm1f(v1);
    v2 = v2 > 0.f ? v2 : expm1f(v2);
    v3 = v3 > 0.f ? v3 : expm1f(v3);

    float s1 = v0 + v1 + v2 + v3;
    float s2 = v0 * v0 + v1 * v1 + v2 * v2 + v3 * v3;
    #pragma unroll
    for (int m = 32; m >= 1; m >>= 1) {
        s1 += __shfl_xor(s1, m, 64);
        s2 += __shfl_xor(s2, m, 64);
    }
    float mu = s1 * (1.f / 256.f);
    float var = s2 * (1.f / 256.f) - mu * mu;
    float rs = rsqrtf(var + LN_EPS);
    float4 g  = *(const float4*)(gamma + d0);
    float4 be = *(const float4*)(beta + d0);
    float4 o;
    o.x = (v0 - mu) * rs * g.x + be.x;
    o.y = (v1 - mu) * rs * g.y + be.y;
    o.z = (v2 - mu) * rs * g.z + be.z;
    o.w = (v3 - mu) * rs * g.w + be.w;
    *(float4*)(out + (size_t)n * DF + d0) = o;
}

extern "C" void kernel_launch(void* const* d_in, const int* in_sizes, int n_in,
                              void* d_out, int out_size, void* d_ws, size_t ws_size,
                              hipStream_t stream)
{
    const float* x     = (const float*)d_in[0];
    const int*   ei    = (const int*)d_in[1];
    const float* W     = (const float*)d_in[2];
    const float* att_s = (const float*)d_in[3];
    const float* att_d = (const float*)d_in[4];
    const float* bias  = (const float*)d_in[5];
    const float* gamma = (const float*)d_in[6];
    const float* beta  = (const float*)d_in[7];
    float* out = (float*)d_out;

    int N = in_sizes[0] / IN_F;
    int E = in_sizes[1] / 2;
    const int* srce = ei;
    const int* dste = ei + E;

    char* wsb = (char*)d_ws;
    size_t off = 0;
    auto alloc = [&](size_t bytes) -> void* {
        void* p = wsb + off;
        off += (bytes + 255) & ~(size_t)255;
        return p;
    };
    f16* hb = (f16*)alloc((size_t)N * DF * sizeof(f16));
    unsigned short* Wp = (unsigned short*)alloc((size_t)IN_F * DF * sizeof(unsigned short));
    float* a_s   = (float*)alloc((size_t)N * 4 * sizeof(float));
    float* a_d   = (float*)alloc((size_t)N * 4 * sizeof(float));
    int*   indeg = (int*)alloc((size_t)N * sizeof(int));
    int*   offs  = (int*)alloc(((size_t)N + 1) * sizeof(int));
    int*   cur   = (int*)alloc((size_t)N * sizeof(int));
    int*   srclist = (int*)alloc((size_t)E * sizeof(int));
    int NB = (N + 1023) / 1024;
    int* part  = (int*)alloc((size_t)NB * sizeof(int));
    int* bloff = (int*)alloc((size_t)NB * sizeof(int));

    (void)hipMemsetAsync(indeg, 0, (size_t)N * sizeof(int), stream);

    k_pack<<<16, 256, 0, stream>>>(W, Wp);
    k_gemm<<<(N + 63) / 64, 256, 0, stream>>>(x, Wp, hb, N);
    k_att<<<(N + 3) / 4, 256, 0, stream>>>(hb, att_s, att_d, a_s, a_d, N);
    k_count<<<2048, 256, 0, stream>>>(dste, E, indeg);
    k_scanA<<<NB, 256, 0, stream>>>(indeg, N, part);
    k_scanB<<<1, 128, 0, stream>>>(part, NB, bloff);
    k_scanC<<<NB, 256, 0, stream>>>(indeg, N, bloff, offs, cur);
    k_scatter<<<2048, 256, 0, stream>>>(srce, dste, E, cur, srclist);
    k_gather<<<(N + 3) / 4, 256, 0, stream>>>(hb, a_s, a_d, offs, srclist, bias, gamma, beta, out, N);
}